// Round 10
// baseline (333.207 us; speedup 1.0000x reference)
//
#include <hip/hip_runtime.h>
#include <float.h>

#define NNODES 30000
#define NEDGES 480000
#define NFEATK 128
#define NH 16
#define NC 32
#define HC 512            // NH*NC
#define NCLASSES 10
#define NG 64
#define CAP 96            // padded per-node edge capacity (max real deg ~45 for Poisson(16))

#define MBP 472           // mb tiles padded to %8==0 so id%8==mb%8 (XCD swizzle); real tiles = 469
#define GEMM_BLOCKS (MBP * 8)
#define SCAT_BLOCKS 1875  // ceil(480000/256)

using half4 = __attribute__((ext_vector_type(4))) _Float16;
using half8 = __attribute__((ext_vector_type(8))) _Float16;
using f32x4 = __attribute__((ext_vector_type(4))) float;

// ---------------- W transposes + cnt zeroing (one dispatch, independent regions) ----------------
__global__ void wconv_kernel(const float* __restrict__ Wl1, const float* __restrict__ Wr1,
                             const float* __restrict__ Wl2, const float* __restrict__ Wr2,
                             _Float16* __restrict__ Wlt1, _Float16* __restrict__ Wrt1,
                             _Float16* __restrict__ Wlt2, _Float16* __restrict__ Wrt2,
                             int* __restrict__ cnt) {
    int gtid = blockIdx.x * blockDim.x + threadIdx.x;
    int gstride = gridDim.x * blockDim.x;
    for (int i = gtid; i < NNODES; i += gstride) cnt[i] = 0;
    for (int i = gtid; i < 2 * 512 * NFEATK; i += gstride) {
        int sel = i >= 512 * NFEATK;
        int idx = i - sel * 512 * NFEATK;
        const float* W = sel ? Wr1 : Wl1;
        _Float16* Wt = sel ? Wrt1 : Wlt1;
        int n = idx & 511, k = idx >> 9;           // reads coalesced over n
        Wt[n * NFEATK + k] = (_Float16)W[idx];
    }
    for (int i = gtid; i < 2 * 512 * NC; i += gstride) {
        int sel = i >= 512 * NC;
        int idx = i - sel * 512 * NC;
        const float* W = sel ? Wr2 : Wl2;
        _Float16* Wt = sel ? Wrt2 : Wlt2;
        int n = idx & 511, k = idx >> 9;
        Wt[n * NC + k] = (_Float16)W[idx];
    }
}

// ---------------- dual MFMA GEMM, XCD-swizzled 1-D grid, optional fused scatter --------
// (unchanged from R9)
template <int K, bool CONVA, bool SCATTER>
__launch_bounds__(256)
__global__ void dual_gemm_kernel(const void* __restrict__ Avoid,
                                 const _Float16* __restrict__ Wlt, const _Float16* __restrict__ Wrt,
                                 const float* __restrict__ bl, const float* __restrict__ br,
                                 _Float16* __restrict__ Yl, _Float16* __restrict__ Yr,
                                 const int* __restrict__ src, const int* __restrict__ dst,
                                 int* __restrict__ cnt, int* __restrict__ csr) {
    constexpr int Kc = K / 8;
    constexpr int AH = 64 * K;
    constexpr int BH = 128 * K;
    constexpr int YSH = 64 * 136;
    constexpr int SMEMH = (AH + BH > YSH) ? (AH + BH) : YSH;
    __shared__ __align__(16) _Float16 smem[SMEMH];
    _Float16* as = smem;
    _Float16* bs = smem + AH;

    int bid = blockIdx.x, tid = threadIdx.x;
    if constexpr (SCATTER) {
        if (bid >= GEMM_BLOCKS) {
            int e = (bid - GEMM_BLOCKS) * 256 + tid;
            if (e < NEDGES) {
                int s = src[e], d = dst[e];
                int pos = atomicAdd(&cnt[d], 1);
                csr[d * CAP + pos] = s;
            }
            return;
        }
    }
    int mb = bid % MBP;
    int yy = bid / MBP;
    if (mb * 64 >= NNODES) return;                 // uniform exit
    int sel = yy >> 2;
    int nbase = (yy & 3) * 128;
    const _Float16* Bt = sel ? Wrt : Wlt;
    const float* bias = sel ? br : bl;
    _Float16* Y = sel ? Yr : Yl;

    for (int c = tid; c < 64 * Kc; c += 256) {
        int row = c / Kc, k8 = c % Kc;
        int arow = mb * 64 + row; if (arow > NNODES - 1) arow = NNODES - 1;
        half8 v;
        if constexpr (CONVA) {
            const float* xp = (const float*)Avoid + (size_t)arow * K + k8 * 8;
            float4 f0 = *(const float4*)xp;
            float4 f1 = *(const float4*)(xp + 4);
            v = half8{(_Float16)f0.x, (_Float16)f0.y, (_Float16)f0.z, (_Float16)f0.w,
                      (_Float16)f1.x, (_Float16)f1.y, (_Float16)f1.z, (_Float16)f1.w};
        } else {
            v = *(const half8*)((const _Float16*)Avoid + (size_t)arow * K + k8 * 8);
        }
        *(half8*)&as[(row * Kc + (k8 ^ (row & (Kc - 1)))) * 8] = v;
    }
    for (int c = tid; c < 128 * Kc; c += 256) {
        int row = c / Kc, k8 = c % Kc;
        half8 v = *(const half8*)&Bt[(size_t)(nbase + row) * K + k8 * 8];
        *(half8*)&bs[(row * Kc + (k8 ^ (row & (Kc - 1)))) * 8] = v;
    }
    __syncthreads();

    int wave = tid >> 6, lane = tid & 63;
    int quad = lane >> 4, l16 = lane & 15;
    int am = l16 & (Kc - 1);

    f32x4 acc[8];
    #pragma unroll
    for (int f = 0; f < 8; f++) acc[f] = (f32x4){0.f, 0.f, 0.f, 0.f};

    #pragma unroll
    for (int kk = 0; kk < Kc; kk += 4) {
        int k8 = (kk + quad) ^ am;
        half8 a = *(const half8*)&as[((wave * 16 + l16) * Kc + k8) * 8];
        #pragma unroll
        for (int f = 0; f < 8; f++) {
            half8 b = *(const half8*)&bs[((f * 16 + l16) * Kc + k8) * 8];
            acc[f] = __builtin_amdgcn_mfma_f32_16x16x32_f16(a, b, acc[f], 0, 0, 0);
        }
    }
    __syncthreads();

    _Float16* ys = smem;
    #pragma unroll
    for (int f = 0; f < 8; f++) {
        float bv = bias[nbase + f * 16 + l16];
        #pragma unroll
        for (int r = 0; r < 4; r++) {
            ys[(wave * 16 + quad * 4 + r) * 136 + f * 16 + l16] = (_Float16)(acc[f][r] + bv);
        }
    }
    __syncthreads();
    int mtop = mb * 64;
    for (int c = tid; c < 64 * 16; c += 256) {
        int r = c >> 4, cc = (c & 15) * 8;
        int grow = mtop + r;
        if (grow < NNODES)
            *(half8*)&Y[(size_t)grow * HC + nbase + cc] = *(half8*)&ys[r * 136 + cc];
    }
}

// ---------------- fused GATv2 edge stage: ONE WAVE PER NODE ----------------
// 128 threads = 2 waves = 2 nodes. Lane owns 8 channels (half8/dwordx4 loads);
// head = 4 lanes -> 2 shuffle levels. Self-loop explicit; bucket holds real edges.
// DS ops/edge 24->8 vs the 128-thread-per-node layout; exp count halved.
template <typename OUT>
__launch_bounds__(128)
__global__ void gat_edge_kernel(const _Float16* __restrict__ xlh, const _Float16* __restrict__ xrh,
                                const float* __restrict__ att, const float* __restrict__ bvec,
                                const int* __restrict__ cnt, const int* __restrict__ csr_src,
                                OUT* __restrict__ hout) {
    __shared__ float red[2][512];
    int w = threadIdx.x >> 6, lane = threadIdx.x & 63;
    int d = blockIdx.x * 2 + w;
    int col = lane * 8;

    half8 xrq = *(const half8*)&xrh[(size_t)d * HC + col];
    float4 at0 = *(const float4*)&att[col];
    float4 at1 = *(const float4*)&att[col + 4];
    float xr[8], at[8];
    #pragma unroll
    for (int c = 0; c < 8; c++) xr[c] = (float)xrq[c];
    at[0] = at0.x; at[1] = at0.y; at[2] = at0.z; at[3] = at0.w;
    at[4] = at1.x; at[5] = at1.y; at[6] = at1.z; at[7] = at1.w;

    int beg = d * CAP, end = beg + cnt[d];

    float l, acc[8];
    // ---- self-loop edge (src = d) ----
    {
        half8 q = *(const half8*)&xlh[(size_t)d * HC + col];
        float xv[8];
        #pragma unroll
        for (int c = 0; c < 8; c++) xv[c] = (float)q[c];
        float v = 0.f;
        #pragma unroll
        for (int c = 0; c < 8; c++) {
            float e = xv[c] + xr[c];
            e = (e > 0.f) ? e : 0.2f * e;
            v += e * at[c];
        }
        v += __shfl_xor(v, 1);
        v += __shfl_xor(v, 2);
        float p = __expf(v);
        l = p;
        #pragma unroll
        for (int c = 0; c < 8; c++) acc[c] = p * xv[c];
    }

    for (int i = beg; i < end; i += 4) {
        int n = end - i;                           // >= 1
        int s0 = csr_src[i];
        int s1 = csr_src[n > 1 ? i + 1 : i];
        int s2 = csr_src[n > 2 ? i + 2 : i];
        int s3 = csr_src[n > 3 ? i + 3 : i];
        half8 q0 = *(const half8*)&xlh[(size_t)s0 * HC + col];
        half8 q1 = *(const half8*)&xlh[(size_t)s1 * HC + col];
        half8 q2 = *(const half8*)&xlh[(size_t)s2 * HC + col];
        half8 q3 = *(const half8*)&xlh[(size_t)s3 * HC + col];
        float xv[4][8];
        #pragma unroll
        for (int c = 0; c < 8; c++) {
            xv[0][c] = (float)q0[c];
            xv[1][c] = (float)q1[c];
            xv[2][c] = (float)q2[c];
            xv[3][c] = (float)q3[c];
        }
        float v0 = 0.f, v1 = 0.f, v2 = 0.f, v3 = 0.f;
        #pragma unroll
        for (int c = 0; c < 8; c++) {
            float e;
            e = xv[0][c] + xr[c]; e = (e > 0.f) ? e : 0.2f * e; v0 += e * at[c];
            e = xv[1][c] + xr[c]; e = (e > 0.f) ? e : 0.2f * e; v1 += e * at[c];
            e = xv[2][c] + xr[c]; e = (e > 0.f) ? e : 0.2f * e; v2 += e * at[c];
            e = xv[3][c] + xr[c]; e = (e > 0.f) ? e : 0.2f * e; v3 += e * at[c];
        }
        v0 += __shfl_xor(v0, 1); v1 += __shfl_xor(v1, 1);
        v2 += __shfl_xor(v2, 1); v3 += __shfl_xor(v3, 1);
        v0 += __shfl_xor(v0, 2); v1 += __shfl_xor(v1, 2);
        v2 += __shfl_xor(v2, 2); v3 += __shfl_xor(v3, 2);
        float p0 = __expf(v0);
        float p1 = (n > 1) ? __expf(v1) : 0.f;
        float p2 = (n > 2) ? __expf(v2) : 0.f;
        float p3 = (n > 3) ? __expf(v3) : 0.f;
        l += (p0 + p1) + (p2 + p3);
        #pragma unroll
        for (int c = 0; c < 8; c++) {
            acc[c] += p0 * xv[0][c] + p1 * xv[1][c];
            acc[c] += p2 * xv[2][c] + p3 * xv[3][c];
        }
    }
    float inv = 1.0f / l;
    #pragma unroll
    for (int c = 0; c < 8; c++) red[w][col + c] = acc[c] * inv;
    __syncthreads();
    if (lane < 32) {
        float s = 0.f;
        #pragma unroll
        for (int hh = 0; hh < NH; ++hh) s += red[w][hh * 32 + lane];
        float r = s * (1.0f / (float)NH) + bvec[lane];
        r = (r > 0.f) ? r : 0.01f * r;             // activation leaky_relu
        hout[d * NC + lane] = (OUT)r;
    }
}

// ---------------- fused pool + classifier: one block per graph ----------------
__launch_bounds__(1024)
__global__ void pool_classify_kernel(const float* __restrict__ h, const int* __restrict__ batch,
                                     const float* __restrict__ Wc, const float* __restrict__ bc,
                                     float* __restrict__ out) {
    int g = blockIdx.x;
    int lo = 0, hi = NNODES;
    while (lo < hi) { int mid = (lo + hi) >> 1; if (batch[mid] < g) lo = mid + 1; else hi = mid; }
    int start = lo;
    hi = NNODES;
    while (lo < hi) { int mid = (lo + hi) >> 1; if (batch[mid] <= g) lo = mid + 1; else hi = mid; }
    int endn = lo;
    int cntg = endn - start;

    int tid = threadIdx.x;
    int c = tid & 31, nl = tid >> 5;              // 32 node-lanes x 32 channels
    float s = 0.f;
    for (int n = start + nl; n < endn; n += 32) s += h[n * NC + c];
    __shared__ float red[1024];
    red[tid] = s;
    __syncthreads();
    if (tid < 32) {
        float t = 0.f;
        #pragma unroll
        for (int j = 0; j < 32; j++) t += red[j * 32 + tid];
        red[tid] = t / fmaxf((float)cntg, 1.0f);
    }
    __syncthreads();
    if (tid < NCLASSES) {
        float sum = bc[tid];
        #pragma unroll
        for (int cc = 0; cc < NC; cc++) sum += red[cc] * Wc[cc * NCLASSES + tid];
        out[g * NCLASSES + tid] = sum;
    }
}

// ---------------- launch ----------------

extern "C" void kernel_launch(void* const* d_in, const int* in_sizes, int n_in,
                              void* d_out, int out_size, void* d_ws, size_t ws_size,
                              hipStream_t stream) {
    const float* x    = (const float*)d_in[0];
    const float* Wl1  = (const float*)d_in[1];
    const float* bl1  = (const float*)d_in[2];
    const float* Wr1  = (const float*)d_in[3];
    const float* br1  = (const float*)d_in[4];
    const float* att1 = (const float*)d_in[5];
    const float* b1   = (const float*)d_in[6];
    const float* Wl2  = (const float*)d_in[7];
    const float* bl2  = (const float*)d_in[8];
    const float* Wr2  = (const float*)d_in[9];
    const float* br2  = (const float*)d_in[10];
    const float* att2 = (const float*)d_in[11];
    const float* b2   = (const float*)d_in[12];
    const float* Wc   = (const float*)d_in[13];
    const float* bc   = (const float*)d_in[14];
    const int* ei     = (const int*)d_in[15];
    const int* batch  = (const int*)d_in[16];
    float* out = (float*)d_out;

    const int* srcp = ei;
    const int* dstp = ei + NEDGES;

    char* ws = (char*)d_ws;
    size_t off = 0;
    auto alloc = [&](size_t bytes) -> void* {
        void* p = ws + off;
        off += (bytes + 255) & ~(size_t)255;
        return p;
    };
    _Float16* xlh  = (_Float16*)alloc(sizeof(_Float16) * (size_t)NNODES * HC);
    _Float16* xrh  = (_Float16*)alloc(sizeof(_Float16) * (size_t)NNODES * HC);
    _Float16* h1   = (_Float16*)alloc(sizeof(_Float16) * (size_t)NNODES * NC);
    float* h2      = (float*)alloc(sizeof(float) * (size_t)NNODES * NC);
    _Float16* Wlt1 = (_Float16*)alloc(sizeof(_Float16) * 512 * NFEATK);
    _Float16* Wrt1 = (_Float16*)alloc(sizeof(_Float16) * 512 * NFEATK);
    _Float16* Wlt2 = (_Float16*)alloc(sizeof(_Float16) * 512 * NC);
    _Float16* Wrt2 = (_Float16*)alloc(sizeof(_Float16) * 512 * NC);
    int*   cnt     = (int*)alloc(sizeof(int) * NNODES);
    int*   csr     = (int*)alloc(sizeof(int) * (size_t)NNODES * CAP);

    // W transposes + cnt zeroing (one dispatch)
    wconv_kernel<<<320, 256, 0, stream>>>(Wl1, Wr1, Wl2, Wr2, Wlt1, Wrt1, Wlt2, Wrt2, cnt);

    // Layer 1 GEMM (reads x fp32, converts inline) + fused edge scatter
    dual_gemm_kernel<NFEATK, true, true><<<GEMM_BLOCKS + SCAT_BLOCKS, 256, 0, stream>>>(
        x, Wlt1, Wrt1, bl1, br1, xlh, xrh, srcp, dstp, cnt, csr);
    gat_edge_kernel<_Float16><<<NNODES / 2, 128, 0, stream>>>(xlh, xrh, att1, b1, cnt, csr, h1);

    // Layer 2
    dual_gemm_kernel<NC, false, false><<<GEMM_BLOCKS, 256, 0, stream>>>(
        h1, Wlt2, Wrt2, bl2, br2, xlh, xrh, nullptr, nullptr, nullptr, nullptr);
    gat_edge_kernel<float><<<NNODES / 2, 128, 0, stream>>>(xlh, xrh, att2, b2, cnt, csr, h2);

    // Pool + classify
    pool_classify_kernel<<<NG, 1024, 0, stream>>>(h2, batch, Wc, bc, out);
}